// Round 1
// baseline (121.861 us; speedup 1.0000x reference)
//
#include <hip/hip_runtime.h>

// ChannelKiller: out[b,c,s] = (c==0) ? x[b,c,s] : 0
// x: [16, 8, 1048576] fp32. Only channel 0 is read (64 MiB); 512 MiB written.
// Memory-bound streaming kernel: float4 grid-stride, wave-uniform channel branch.

#define SAMPLES_LOG2_F4 18  // 1048576 floats / 4 per float4 = 2^18 float4 per channel

__global__ void ChannelKiller_54365696033605_kernel(const float4* __restrict__ x,
                                                    float4* __restrict__ out,
                                                    int n4) {
    int i = blockIdx.x * blockDim.x + threadIdx.x;
    const int stride = gridDim.x * blockDim.x;
    const float4 zero = make_float4(0.f, 0.f, 0.f, 0.f);
    for (; i < n4; i += stride) {
        // channel = (flat_float4_index >> 18) & 7  (8 channels per batch)
        int c = (i >> SAMPLES_LOG2_F4) & 7;
        if (c == 0) {
            out[i] = x[i];   // channel 0: copy (only 1/8 of input is ever read)
        } else {
            out[i] = zero;   // other channels: pure store, no load
        }
    }
}

extern "C" void kernel_launch(void* const* d_in, const int* in_sizes, int n_in,
                              void* d_out, int out_size, void* d_ws, size_t ws_size,
                              hipStream_t stream) {
    const float4* x = (const float4*)d_in[0];
    float4* out = (float4*)d_out;
    int n4 = out_size / 4;  // 134217728 / 4 = 33554432 float4

    const int block = 256;
    // Streaming: ~2048 blocks (8 per CU) + grid-stride covers the rest.
    int grid = 2048;
    ChannelKiller_54365696033605_kernel<<<grid, block, 0, stream>>>(x, out, n4);
}